// Round 9
// baseline (399.632 us; speedup 1.0000x reference)
//
#include <hip/hip_runtime.h>
#include <hip/hip_bf16.h>
#include <math.h>

// Problem constants (fixed by setup_inputs)
#define Bq 8
#define Nq 2048
#define Pq 64
#define Dq 128
#define Kq 16
#define BNq (Bq * Nq)   // 16384 points total

typedef unsigned short u16;
typedef __bf16 bf16x8v __attribute__((ext_vector_type(8)));
typedef float f32x4v __attribute__((ext_vector_type(4)));

__device__ __forceinline__ u16 f2b(float f) {
    return __builtin_bit_cast(u16, (__bf16)f);      // RNE
}
__device__ __forceinline__ float b2f(u16 u) {
    return (float)__builtin_bit_cast(__bf16, u);
}

// Raw barrier: orders LDS producer/consumer WITHOUT draining vmcnt —
// global prefetch loads stay in flight across it. The "memory" clobber is a
// compiler fence for memory ops (incl. compiler-generated ds_reads), so no
// sched_barrier(0) is needed; round-7 showed sched_barrier(0) pins prefetched
// values live across barriers -> 128-VGPR cap exceeded -> 235 MB scratch spill.
#define BARRIER() do { asm volatile("s_waitcnt lgkmcnt(0)" ::: "memory"); \
                       __builtin_amdgcn_s_barrier(); } while (0)

// Wt element offsets (all matrices stored transposed bf16: Wt[n][k] = W[k][n])
#define OFF_DEL2 0
#define OFF_GAM1 16384
#define OFF_GAM2 32768
#define OFF_FC1  49152
#define OFF_PHI  57344
#define OFF_PSI  73728
#define OFF_ALF  90112
#define OFF_DPT1 106496
#define OFF_DPT2 122880
#define WT_TOTAL 139264

// ---------------------------------------------------------------------------
// Kernel 0: transpose+convert all 9 matmul weights -> bf16 Wt[n][K] linear.
// ---------------------------------------------------------------------------
__global__ __launch_bounds__(256) void prep_kernel(
    const float* __restrict__ Wdel2, const float* __restrict__ Wgam1,
    const float* __restrict__ Wgam2, const float* __restrict__ Wfc1,
    const float* __restrict__ Wphi, const float* __restrict__ Wpsi,
    const float* __restrict__ Walpha, const float* __restrict__ Wdpt1,
    const float* __restrict__ Wdpt2, u16* __restrict__ Wt) {
    int idx = blockIdx.x * 256 + threadIdx.x;       // 0..139263
    const float* W;
    int n, k;
    if (idx < OFF_FC1) {
        int m = idx >> 14, r = idx & 16383;
        W = (m == 0) ? Wdel2 : (m == 1) ? Wgam1 : Wgam2;
        n = r >> 7; k = r & 127;
    } else if (idx < OFF_PHI) {
        int r = idx - OFF_FC1;
        W = Wfc1; n = r >> 6; k = r & 63;
    } else {
        int r = idx - OFF_PHI;
        int m = r >> 14; r &= 16383;
        W = (m == 0) ? Wphi : (m == 1) ? Wpsi : (m == 2) ? Walpha : (m == 3) ? Wdpt1 : Wdpt2;
        n = r >> 7; k = r & 127;
    }
    Wt[idx] = f2b(W[k * 128 + n]);
}

// ---------------------------------------------------------------------------
// Kernel 1 (v2): exact kNN. 512 blocks x 256 threads. (measured-good)
// ---------------------------------------------------------------------------
__global__ __launch_bounds__(256) void knn_kernel(const float* __restrict__ x,
                                                  int* __restrict__ knn) {
    __shared__ float4 sx[Nq];                       // 32 KB
    __shared__ float sLd[32][8][17];
    __shared__ int   sLi[32][8][17];
    const int b = blockIdx.x >> 6;
    const int q0 = (blockIdx.x & 63) * 32;
    const float* xb = x + b * Nq * 3;
    for (int j = threadIdx.x; j < Nq; j += 256) {
        float x0 = xb[j * 3 + 0], x1 = xb[j * 3 + 1], x2 = xb[j * 3 + 2];
        // replicate jnp.sum(x*x): no fma contraction
        float n2 = __fadd_rn(__fadd_rn(__fmul_rn(x0, x0), __fmul_rn(x1, x1)),
                             __fmul_rn(x2, x2));
        sx[j] = make_float4(x0, x1, x2, n2);
    }
    __syncthreads();
    const int q = threadIdx.x & 31;
    const int sub = threadIdx.x >> 5;
    const float4 qv = sx[q0 + q];
    float bd[Kq];
    int bj[Kq];
#pragma unroll
    for (int s = 0; s < Kq; ++s) { bd[s] = INFINITY; bj[s] = 0; }
    const int j0 = sub * 256;
    for (int i = 0; i < 256; ++i) {
        const int j = j0 + i;
        float4 p = sx[j];
        float dot = __fadd_rn(__fadd_rn(__fmul_rn(qv.x, p.x), __fmul_rn(qv.y, p.y)),
                              __fmul_rn(qv.z, p.z));
        float d = __fsub_rn(__fadd_rn(qv.w, p.w), __fmul_rn(2.0f, dot));
        if (d < bd[Kq - 1]) {                       // strict <: stable
            bd[Kq - 1] = d; bj[Kq - 1] = j;
#pragma unroll
            for (int s = Kq - 1; s >= 1; --s) {
                if (bd[s] < bd[s - 1]) {
                    float td = bd[s]; bd[s] = bd[s - 1]; bd[s - 1] = td;
                    int tj = bj[s]; bj[s] = bj[s - 1]; bj[s - 1] = tj;
                }
            }
        }
    }
#pragma unroll
    for (int s = 0; s < Kq; ++s) { sLd[q][sub][s] = bd[s]; sLi[q][sub][s] = bj[s]; }
    __syncthreads();
    if (threadIdx.x < 32) {
        const int mq = threadIdx.x;
        int pos[8]; float hd[8]; int hi[8];
#pragma unroll
        for (int s = 0; s < 8; ++s) {
            pos[s] = 1; hd[s] = sLd[mq][s][0]; hi[s] = sLi[mq][s][0];
        }
        int* o = knn + (b * Nq + q0 + mq) * Kq;
#pragma unroll
        for (int oi = 0; oi < Kq; ++oi) {
            float bdv = hd[0]; int biv = hi[0]; int bs = 0;
#pragma unroll
            for (int s = 1; s < 8; ++s) {
                bool take = (hd[s] < bdv) || (hd[s] == bdv && hi[s] < biv);
                if (take) { bdv = hd[s]; biv = hi[s]; bs = s; }
            }
            o[oi] = biv;
#pragma unroll
            for (int s = 0; s < 8; ++s) {           // static-index update
                if (s == bs) {
                    int pp = pos[s] < Kq ? pos[s] : (Kq - 1);
                    bool ok = pos[s] < Kq;
                    hd[s] = ok ? sLd[mq][s][pp] : INFINITY;
                    hi[s] = ok ? sLi[mq][s][pp] : 0x7fffffff;
                    pos[s]++;
                }
            }
        }
    }
}

// ---------------------------------------------------------------------------
// Shared MFMA helpers (feat kernel). XOR swizzle byte ^= (row&7)<<4.
// ---------------------------------------------------------------------------
template <int BYTES, int ROWBYTES>
__device__ __forceinline__ void stageW(const u16* __restrict__ src,
                                       u16* __restrict__ sW, int t) {
#pragma unroll
    for (int c = 0; c < BYTES / 4096; ++c) {
        int lin = c * 4096 + t * 16;
        int n = lin / ROWBYTES;
        int o = lin % ROWBYTES;
        bf16x8v v = *(const bf16x8v*)((const char*)src + lin);
        *(bf16x8v*)((char*)sW + n * ROWBYTES + (o ^ ((n & 7) << 4))) = v;
    }
}

__device__ __forceinline__ void mfma_k128(const u16* __restrict__ sA,
                                          const u16* __restrict__ sW,
                                          int colbase, int lane,
                                          f32x4v (&acc)[4][2]) {
    const int kg = lane >> 4;
    const int l15 = lane & 15;
#pragma unroll
    for (int ks = 0; ks < 4; ++ks) {
        bf16x8v a[4], bfr[2];
#pragma unroll
        for (int m = 0; m < 4; ++m) {
            int row = m * 16 + l15;
            int o = (ks * 64 + kg * 16) ^ ((row & 7) << 4);
            a[m] = *(const bf16x8v*)((const char*)sA + row * 256 + o);
        }
#pragma unroll
        for (int nt = 0; nt < 2; ++nt) {
            int n = colbase + nt * 16 + l15;
            int o = (ks * 64 + kg * 16) ^ ((n & 7) << 4);
            bfr[nt] = *(const bf16x8v*)((const char*)sW + n * 256 + o);
        }
#pragma unroll
        for (int m = 0; m < 4; ++m)
#pragma unroll
            for (int nt = 0; nt < 2; ++nt)
                acc[m][nt] = __builtin_amdgcn_mfma_f32_16x16x32_bf16(a[m], bfr[nt], acc[m][nt], 0, 0, 0);
    }
}

__device__ __forceinline__ void mfma_k64(const u16* __restrict__ sA,
                                         const u16* __restrict__ sW,
                                         int colbase, int lane,
                                         f32x4v (&acc)[4][2]) {
    const int kg = lane >> 4;
    const int l15 = lane & 15;
#pragma unroll
    for (int ks = 0; ks < 2; ++ks) {
        bf16x8v a[4], bfr[2];
#pragma unroll
        for (int m = 0; m < 4; ++m) {
            int row = m * 16 + l15;
            int o = (ks * 64 + kg * 16) ^ ((row & 7) << 4);
            a[m] = *(const bf16x8v*)((const char*)sA + row * 128 + o);
        }
#pragma unroll
        for (int nt = 0; nt < 2; ++nt) {
            int n = colbase + nt * 16 + l15;
            int o = (ks * 64 + kg * 16) ^ ((n & 7) << 4);
            bfr[nt] = *(const bf16x8v*)((const char*)sW + n * 128 + o);
        }
#pragma unroll
        for (int m = 0; m < 4; ++m)
#pragma unroll
            for (int nt = 0; nt < 2; ++nt)
                acc[m][nt] = __builtin_amdgcn_mfma_f32_16x16x32_bf16(a[m], bfr[nt], acc[m][nt], 0, 0, 0);
    }
}

// ---------------------------------------------------------------------------
// Kernel 2 (MFMA): per-point features, 64 points/block, 256 blocks x 4 waves.
// (unchanged from round 3/5)
// ---------------------------------------------------------------------------
__global__ __launch_bounds__(256, 2) void feat_kernel(
    const float* __restrict__ in_f, const u16* __restrict__ Wt,
    const float* __restrict__ bfc1, const float* __restrict__ bdpt1,
    const float* __restrict__ bdpt2,
    float* __restrict__ base, u16* __restrict__ psiB, u16* __restrict__ alphaB) {
    __shared__ __align__(16) u16 sIn[64 * 64];      // 8 KB
    __shared__ __align__(16) u16 sF[64 * 128];      // 16 KB
    __shared__ __align__(16) u16 sW[128 * 128];     // 32 KB
    const int t = threadIdx.x;
    const int lane = t & 63;
    const int w = t >> 6;
    const int kg = lane >> 4;
    const int l15 = lane & 15;
    const int p0 = blockIdx.x * 64;

    {
        const int r = t >> 2;
        const int c0 = (t & 3) * 16;
        const float* src = &in_f[(size_t)(p0 + r) * 64 + c0];
        float4 v0 = *(const float4*)(src + 0);
        float4 v1 = *(const float4*)(src + 4);
        float4 v2 = *(const float4*)(src + 8);
        float4 v3 = *(const float4*)(src + 12);
        bf16x8v lo, hi;
        lo[0] = (__bf16)v0.x; lo[1] = (__bf16)v0.y; lo[2] = (__bf16)v0.z; lo[3] = (__bf16)v0.w;
        lo[4] = (__bf16)v1.x; lo[5] = (__bf16)v1.y; lo[6] = (__bf16)v1.z; lo[7] = (__bf16)v1.w;
        hi[0] = (__bf16)v2.x; hi[1] = (__bf16)v2.y; hi[2] = (__bf16)v2.z; hi[3] = (__bf16)v2.w;
        hi[4] = (__bf16)v3.x; hi[5] = (__bf16)v3.y; hi[6] = (__bf16)v3.z; hi[7] = (__bf16)v3.w;
        const int swz = (r & 7) << 4;
        *(bf16x8v*)((char*)sIn + r * 128 + ((c0 * 2) ^ swz)) = lo;
        *(bf16x8v*)((char*)sIn + r * 128 + (((c0 + 8) * 2) ^ swz)) = hi;
    }

    f32x4v acc[4][2], accPhi[4][2];

    {
        float bv0 = bfc1[w * 32 + l15];
        float bv1 = bfc1[w * 32 + 16 + l15];
#pragma unroll
        for (int m = 0; m < 4; ++m) { acc[m][0] = f32x4v{bv0, bv0, bv0, bv0}; acc[m][1] = f32x4v{bv1, bv1, bv1, bv1}; }
    }
    stageW<16384, 128>(Wt + OFF_FC1, sW, t);
    __syncthreads();
    mfma_k64(sIn, sW, w * 32, lane, acc);

#pragma unroll
    for (int m = 0; m < 4; ++m)
#pragma unroll
        for (int nt = 0; nt < 2; ++nt)
#pragma unroll
            for (int rr = 0; rr < 4; ++rr) {
                int row = m * 16 + kg * 4 + rr;
                int col = w * 32 + nt * 16 + l15;
                *(__bf16*)((char*)sF + row * 256 + ((col * 2) ^ ((row & 7) << 4))) = (__bf16)acc[m][nt][rr];
            }

#pragma unroll
    for (int m = 0; m < 4; ++m) { accPhi[m][0] = f32x4v{0, 0, 0, 0}; accPhi[m][1] = f32x4v{0, 0, 0, 0}; }
    __syncthreads();
    stageW<32768, 256>(Wt + OFF_PHI, sW, t);
    __syncthreads();
    mfma_k128(sF, sW, w * 32, lane, accPhi);

#pragma unroll
    for (int m = 0; m < 4; ++m) { acc[m][0] = f32x4v{0, 0, 0, 0}; acc[m][1] = f32x4v{0, 0, 0, 0}; }
    __syncthreads();
    stageW<32768, 256>(Wt + OFF_PSI, sW, t);
    __syncthreads();
    mfma_k128(sF, sW, w * 32, lane, acc);
#pragma unroll
    for (int m = 0; m < 4; ++m)
#pragma unroll
        for (int nt = 0; nt < 2; ++nt)
#pragma unroll
            for (int rr = 0; rr < 4; ++rr) {
                int row = m * 16 + kg * 4 + rr;
                int col = w * 32 + nt * 16 + l15;
                psiB[(size_t)(p0 + row) * 128 + col] = f2b(acc[m][nt][rr]);
            }

#pragma unroll
    for (int m = 0; m < 4; ++m) { acc[m][0] = f32x4v{0, 0, 0, 0}; acc[m][1] = f32x4v{0, 0, 0, 0}; }
    __syncthreads();
    stageW<32768, 256>(Wt + OFF_ALF, sW, t);
    __syncthreads();
    mfma_k128(sF, sW, w * 32, lane, acc);
#pragma unroll
    for (int m = 0; m < 4; ++m)
#pragma unroll
        for (int nt = 0; nt < 2; ++nt)
#pragma unroll
            for (int rr = 0; rr < 4; ++rr) {
                int row = m * 16 + kg * 4 + rr;
                int col = w * 32 + nt * 16 + l15;
                alphaB[(size_t)(p0 + row) * 128 + col] = f2b(acc[m][nt][rr]);
            }

    {
        float bv0 = bdpt1[w * 32 + l15];
        float bv1 = bdpt1[w * 32 + 16 + l15];
#pragma unroll
        for (int m = 0; m < 4; ++m) { acc[m][0] = f32x4v{bv0, bv0, bv0, bv0}; acc[m][1] = f32x4v{bv1, bv1, bv1, bv1}; }
    }
    __syncthreads();
    stageW<32768, 256>(Wt + OFF_DPT1, sW, t);
    __syncthreads();
    mfma_k128(sF, sW, w * 32, lane, acc);
    __syncthreads();
#pragma unroll
    for (int m = 0; m < 4; ++m)
#pragma unroll
        for (int nt = 0; nt < 2; ++nt)
#pragma unroll
            for (int rr = 0; rr < 4; ++rr) {
                int row = m * 16 + kg * 4 + rr;
                int col = w * 32 + nt * 16 + l15;
                *(__bf16*)((char*)sF + row * 256 + ((col * 2) ^ ((row & 7) << 4))) =
                    (__bf16)fmaxf(acc[m][nt][rr], 0.f);
            }

    {
        float bv0 = bdpt2[w * 32 + l15];
        float bv1 = bdpt2[w * 32 + 16 + l15];
#pragma unroll
        for (int m = 0; m < 4; ++m) { acc[m][0] = f32x4v{bv0, bv0, bv0, bv0}; acc[m][1] = f32x4v{bv1, bv1, bv1, bv1}; }
    }
    __syncthreads();
    stageW<32768, 256>(Wt + OFF_DPT2, sW, t);
    __syncthreads();
    mfma_k128(sF, sW, w * 32, lane, acc);
#pragma unroll
    for (int m = 0; m < 4; ++m)
#pragma unroll
        for (int nt = 0; nt < 2; ++nt)
#pragma unroll
            for (int rr = 0; rr < 4; ++rr) {
                int row = m * 16 + kg * 4 + rr;
                int col = w * 32 + nt * 16 + l15;
                base[(size_t)(p0 + row) * 128 + col] = acc[m][nt][rr] + accPhi[m][nt][rr];
            }
}

// ---------------------------------------------------------------------------
// Kernel 3 (v6): 1024 blocks x 512 threads, 4 chunks x 4 points.
// = round-7 structure minus sched_barrier(0) (spill fix) with alpha gather
// moved to just before gam2 (1-stage live range instead of 3).
// ---------------------------------------------------------------------------
__device__ __forceinline__ void mfma_ldsB(const u16* __restrict__ sA,
                                          const u16* __restrict__ sW,
                                          int colW, int kg, int l15,
                                          f32x4v (&acc)[4]) {
#pragma unroll
    for (int ks = 0; ks < 4; ++ks) {
        bf16x8v a[4], bb;
#pragma unroll
        for (int m = 0; m < 4; ++m) {
            int row = m * 16 + l15;
            int o = (ks * 64 + kg * 16) ^ ((row & 7) << 4);
            a[m] = *(const bf16x8v*)((const char*)sA + row * 256 + o);
        }
        {
            int o = (ks * 64 + kg * 16) ^ ((colW & 7) << 4);
            bb = *(const bf16x8v*)((const char*)sW + colW * 256 + o);
        }
#pragma unroll
        for (int m = 0; m < 4; ++m)
            acc[m] = __builtin_amdgcn_mfma_f32_16x16x32_bf16(a[m], bb, acc[m], 0, 0, 0);
    }
}

__device__ __forceinline__ void mfma_regB(const u16* __restrict__ sA,
                                          const bf16x8v (&wB)[4],
                                          int kg, int l15,
                                          f32x4v (&acc)[4]) {
#pragma unroll
    for (int ks = 0; ks < 4; ++ks) {
#pragma unroll
        for (int m = 0; m < 4; ++m) {
            int row = m * 16 + l15;
            int o = (ks * 64 + kg * 16) ^ ((row & 7) << 4);
            bf16x8v a = *(const bf16x8v*)((const char*)sA + row * 256 + o);
            acc[m] = __builtin_amdgcn_mfma_f32_16x16x32_bf16(a, wB[ks], acc[m], 0, 0, 0);
        }
    }
}

__global__ __launch_bounds__(512, 4) void main_kernel(
    const float* __restrict__ x, const float* __restrict__ in_f,
    const float* __restrict__ Wdel1, const float* __restrict__ bdel1,
    const float* __restrict__ bdel2,
    const float* __restrict__ bgam1, const float* __restrict__ bgam2,
    const float* __restrict__ Wfc2, const float* __restrict__ bfc2,
    const float* __restrict__ base, const u16* __restrict__ psiB,
    const u16* __restrict__ alphaB, const int* __restrict__ knn,
    const u16* __restrict__ Wt, float* __restrict__ out) {
    __shared__ __align__(16) u16 sWd2[128 * 128];   // 32 KB del2 weights (swz)
    __shared__ __align__(16) u16 sA[2][64 * 128];   // 2x16 KB ping-pong (swz)
    __shared__ float sWd1[512];                     // Wdel1 rows + bias at 384
    __shared__ float sY[4][128];

    const int t = threadIdx.x;
    const int lane = t & 63;
    const int w = t >> 6;                            // wave 0..7
    const int kg = lane >> 4;
    const int l15 = lane & 15;
    const int colW = w * 16 + l15;                   // this thread's out column

    const int pbase = blockIdx.x * 16;               // 16 points per block
    const int b = pbase >> 11;
    const int bN = b * Nq;
    const int hr = t >> 3;                           // B-phase row 0..63
    const int hc0 = (t & 7) * 16;                    // B-phase col base

    // ---- chunk-0 B inputs (issued early; drained at prologue barrier) ----
    int pB = pbase + (hr >> 4);
    int jB = knn[pB * Kq + (hr & 15)];
    float cxq0 = x[(size_t)pB * 3 + 0];
    float cxq1 = x[(size_t)pB * 3 + 1];
    float cxq2 = x[(size_t)pB * 3 + 2];
    float cxn0 = x[(size_t)(bN + jB) * 3 + 0];
    float cxn1 = x[(size_t)(bN + jB) * 3 + 1];
    float cxn2 = x[(size_t)(bN + jB) * 3 + 2];

    // ---- prologue: del2 weights -> LDS, Wdel1 -> LDS, gam weights -> regs ----
#pragma unroll
    for (int c = 0; c < 4; ++c) {
        int lin = c * 8192 + t * 16;
        int n = lin >> 8;
        int o = lin & 255;
        bf16x8v v = *(const bf16x8v*)((const char*)(Wt + OFF_DEL2) + lin);
        *(bf16x8v*)((char*)sWd2 + n * 256 + (o ^ ((n & 7) << 4))) = v;
    }
    sWd1[t] = (t < 384) ? Wdel1[t] : bdel1[t - 384];
    bf16x8v wG1[4], wG2[4];
#pragma unroll
    for (int ks = 0; ks < 4; ++ks) {
        size_t off = (size_t)colW * 128 + ks * 32 + kg * 8;
        wG1[ks] = *(const bf16x8v*)(Wt + OFF_GAM1 + off);
        wG2[ks] = *(const bf16x8v*)(Wt + OFF_GAM2 + off);
    }
    const float bD = bdel2[colW];
    const float bG1 = bgam1[colW];
    const float bG2 = bgam2[colW];
    const float bOq = bfc2[(t & 127) >> 1];
    __syncthreads();    // prologue fence: sWd1/sWd2 visible before chunk 0

    for (int c = 0; c < 4; ++c) {
        const int p0 = pbase + c * 4;
        u16* sAh = sA[c & 1];                        // h1 then g1
        u16* sAp = sA[1 - (c & 1)];                  // pre

        // ---- B: h1 = relu(diff @ Wdel1 + b) -> sAh ----
        {
            const float dx = cxq0 - cxn0;
            const float dy = cxq1 - cxn1;
            const float dz = cxq2 - cxn2;
            const int swzB = (hr & 7) << 4;
#pragma unroll
            for (int hh = 0; hh < 2; ++hh) {
                bf16x8v hv;
#pragma unroll
                for (int c4 = 0; c4 < 2; ++c4) {
                    const int cc = hc0 + hh * 8 + c4 * 4;
                    float4 wx = *(const float4*)&sWd1[cc];
                    float4 wy = *(const float4*)&sWd1[128 + cc];
                    float4 wz = *(const float4*)&sWd1[256 + cc];
                    float4 b4 = *(const float4*)&sWd1[384 + cc];
                    hv[c4 * 4 + 0] = (__bf16)fmaxf(fmaf(dz, wz.x, fmaf(dy, wy.x, fmaf(dx, wx.x, b4.x))), 0.f);
                    hv[c4 * 4 + 1] = (__bf16)fmaxf(fmaf(dz, wz.y, fmaf(dy, wy.y, fmaf(dx, wx.y, b4.y))), 0.f);
                    hv[c4 * 4 + 2] = (__bf16)fmaxf(fmaf(dz, wz.z, fmaf(dy, wy.z, fmaf(dx, wx.z, b4.z))), 0.f);
                    hv[c4 * 4 + 3] = (__bf16)fmaxf(fmaf(dz, wz.w, fmaf(dy, wy.w, fmaf(dx, wx.w, b4.w))), 0.f);
                }
                *(bf16x8v*)((char*)sAh + hr * 256 + (((hc0 + hh * 8) * 2) ^ swzB)) = hv;
            }
        }

        // ---- prefetch: per-thread knn idx, then psi + base (consumed post-MFMA) ----
        int4 ivv[4];
#pragma unroll
        for (int m = 0; m < 4; ++m)
            ivv[m] = *(const int4*)&knn[(p0 + m) * Kq + kg * 4];
        u16 ps[4][4];
        float bs[4];
#pragma unroll
        for (int m = 0; m < 4; ++m) {
            bs[m] = base[(size_t)(p0 + m) * 128 + colW];
            const int ii[4] = {ivv[m].x, ivv[m].y, ivv[m].z, ivv[m].w};
#pragma unroll
            for (int rr = 0; rr < 4; ++rr)
                ps[m][rr] = psiB[(size_t)(bN + ii[rr]) * 128 + colW];
        }
        BARRIER();                                   // bar1: h1 ready

        // ---- del2: delta = h1 @ Wdel2 + b ----
        f32x4v accD[4];
#pragma unroll
        for (int m = 0; m < 4; ++m) accD[m] = f32x4v{bD, bD, bD, bD};
        mfma_ldsB(sAh, sWd2, colW, kg, l15, accD);

        // ---- pre = delta + (base - psi) -> sAp (prefetched regs) ----
#pragma unroll
        for (int m = 0; m < 4; ++m)
#pragma unroll
            for (int rr = 0; rr < 4; ++rr) {
                int row = m * 16 + kg * 4 + rr;
                int off = row * 256 + ((colW * 2) ^ ((row & 7) << 4));
                *(__bf16*)((char*)sAp + off) = (__bf16)(accD[m][rr] + (bs[m] - b2f(ps[m][rr])));
            }
        BARRIER();                                   // bar2: pre ready

        // ---- gam1 (reg weights): g1 = relu(pre @ Wgam1 + b) -> sAh ----
        f32x4v accT[4];
#pragma unroll
        for (int m = 0; m < 4; ++m) accT[m] = f32x4v{bG1, bG1, bG1, bG1};
        mfma_regB(sAp, wG1, kg, l15, accT);
#pragma unroll
        for (int m = 0; m < 4; ++m)
#pragma unroll
            for (int rr = 0; rr < 4; ++rr) {
                int row = m * 16 + kg * 4 + rr;
                int off = row * 256 + ((colW * 2) ^ ((row & 7) << 4));
                *(__bf16*)((char*)sAh + off) = (__bf16)fmaxf(accT[m][rr], 0.f);
            }
        BARRIER();                                   // bar3: g1 ready

        // ---- prefetch alpha (1 stage early; consumed right after gam2) ----
        u16 al[4][4];
#pragma unroll
        for (int m = 0; m < 4; ++m) {
            const int ii[4] = {ivv[m].x, ivv[m].y, ivv[m].z, ivv[m].w};
#pragma unroll
            for (int rr = 0; rr < 4; ++rr)
                al[m][rr] = alphaB[(size_t)(bN + ii[rr]) * 128 + colW];
        }

        // ---- gam2 (reg weights) ----
#pragma unroll
        for (int m = 0; m < 4; ++m) accT[m] = f32x4v{bG2, bG2, bG2, bG2};
        mfma_regB(sAh, wG2, kg, l15, accT);

        // ---- prefetch next-chunk B idx (x loads issued after out) ----
        const int pN = pbase + (c + 1) * 4 + (hr >> 4);
        int jN = 0;
        if (c < 3) jN = knn[pN * Kq + (hr & 15)];

        // ---- softmax over k + y (alpha from regs) ----
#pragma unroll
        for (int m = 0; m < 4; ++m) {
            float g0 = accT[m][0], g1v = accT[m][1], g2 = accT[m][2], g3 = accT[m][3];
            float mx = fmaxf(fmaxf(g0, g1v), fmaxf(g2, g3));
            mx = fmaxf(mx, __shfl_xor(mx, 16, 64));
            mx = fmaxf(mx, __shfl_xor(mx, 32, 64));
            float m4 = mx * 0.25f;
            float e0 = expf(0.25f * g0 - m4), e1 = expf(0.25f * g1v - m4);
            float e2 = expf(0.25f * g2 - m4), e3 = expf(0.25f * g3 - m4);
            float s = e0 + e1 + e2 + e3;
            s += __shfl_xor(s, 16, 64);
            s += __shfl_xor(s, 32, 64);
            float y = fmaf(e0, b2f(al[m][0]) + accD[m][0],
                      fmaf(e1, b2f(al[m][1]) + accD[m][1],
                      fmaf(e2, b2f(al[m][2]) + accD[m][2],
                           e3 * (b2f(al[m][3]) + accD[m][3]))));
            y += __shfl_xor(y, 16, 64);
            y += __shfl_xor(y, 32, 64);
            if (kg == 0) sY[m][colW] = y / s;
        }
        BARRIER();                                   // bar4: sY ready

        // ---- out = y @ Wfc2 + b + in_f (all 8 waves, lane-paired) ----
        {
            const int p = t >> 7;                    // 0..3
            const int q = (t & 127) >> 1;
            const int half = t & 1;
            const int gp = p0 + p;
            float a = 0.f;
            const float* wcol = Wfc2 + (half * 64) * 64 + q;
#pragma unroll 16
            for (int d = 0; d < 64; ++d)
                a = fmaf(sY[p][half * 64 + d], wcol[d * 64], a);
            a += __shfl_xor(a, 1, 64);
            if (half == 0)
                out[(size_t)gp * 64 + q] = a + bOq + in_f[(size_t)gp * 64 + q];
        }

        // ---- prefetch next-chunk x (covered by loop-back to B compute) ----
        if (c < 3) {
            cxq0 = x[(size_t)pN * 3 + 0];
            cxq1 = x[(size_t)pN * 3 + 1];
            cxq2 = x[(size_t)pN * 3 + 2];
            cxn0 = x[(size_t)(bN + jN) * 3 + 0];
            cxn1 = x[(size_t)(bN + jN) * 3 + 1];
            cxn2 = x[(size_t)(bN + jN) * 3 + 2];
        }
    }
}

// ---------------------------------------------------------------------------
extern "C" void kernel_launch(void* const* d_in, const int* in_sizes, int n_in,
                              void* d_out, int out_size, void* d_ws, size_t ws_size,
                              hipStream_t stream) {
    const float* x     = (const float*)d_in[0];
    const float* in_f  = (const float*)d_in[1];
    const float* Wfc1  = (const float*)d_in[2];
    const float* bfc1  = (const float*)d_in[3];
    const float* Wphi  = (const float*)d_in[4];
    const float* Wpsi  = (const float*)d_in[5];
    const float* Walpha= (const float*)d_in[6];
    const float* Wdpt1 = (const float*)d_in[7];
    const float* bdpt1 = (const float*)d_in[8];
    const float* Wdpt2 = (const float*)d_in[9];
    const float* bdpt2 = (const float*)d_in[10];
    const float* Wgam1 = (const float*)d_in[11];
    const float* bgam1 = (const float*)d_in[12];
    const float* Wgam2 = (const float*)d_in[13];
    const float* bgam2 = (const float*)d_in[14];
    const float* Wdel1 = (const float*)d_in[15];
    const float* bdel1 = (const float*)d_in[16];
    const float* Wdel2 = (const float*)d_in[17];
    const float* bdel2 = (const float*)d_in[18];
    const float* Wfc2  = (const float*)d_in[19];
    const float* bfc2  = (const float*)d_in[20];
    float* out = (float*)d_out;

    // ws: base f32 (8MB) | psiB bf16 (4MB) | alphaB bf16 (4MB) | knn (1MB) | Wt (272KB)
    float* base   = (float*)d_ws;
    u16*   psiB   = (u16*)(base + (size_t)BNq * Dq);
    u16*   alphaB = psiB + (size_t)BNq * Dq;
    int*   knn    = (int*)(alphaB + (size_t)BNq * Dq);
    u16*   Wt     = (u16*)(knn + (size_t)BNq * Kq);

    prep_kernel<<<WT_TOTAL / 256, 256, 0, stream>>>(Wdel2, Wgam1, Wgam2, Wfc1, Wphi,
                                                    Wpsi, Walpha, Wdpt1, Wdpt2, Wt);
    knn_kernel<<<512, 256, 0, stream>>>(x, knn);
    feat_kernel<<<BNq / 64, 256, 0, stream>>>(in_f, Wt, bfc1, bdpt1, bdpt2,
                                              base, psiB, alphaB);
    main_kernel<<<BNq / 16, 512, 0, stream>>>(x, in_f, Wdel1, bdel1, bdel2,
                                              bgam1, bgam2, Wfc2, bfc2,
                                              base, psiB, alphaB, knn, Wt, out);
}

// Round 10
// 282.481 us; speedup vs baseline: 1.4147x; 1.4147x over previous
//
#include <hip/hip_runtime.h>
#include <hip/hip_bf16.h>
#include <math.h>

// Problem constants (fixed by setup_inputs)
#define Bq 8
#define Nq 2048
#define Pq 64
#define Dq 128
#define Kq 16
#define BNq (Bq * Nq)   // 16384 points total

typedef unsigned short u16;
typedef __bf16 bf16x8v __attribute__((ext_vector_type(8)));
typedef float f32x4v __attribute__((ext_vector_type(4)));

__device__ __forceinline__ u16 f2b(float f) {
    return __builtin_bit_cast(u16, (__bf16)f);      // RNE
}
__device__ __forceinline__ float b2f(u16 u) {
    return (float)__builtin_bit_cast(__bf16, u);
}

// Raw barrier: orders LDS producer/consumer WITHOUT draining vmcnt —
// global prefetch loads stay in flight across it.
#define BARRIER() do { asm volatile("s_waitcnt lgkmcnt(0)" ::: "memory"); \
                       __builtin_amdgcn_s_barrier(); } while (0)

// Wt element offsets (all matrices stored transposed bf16: Wt[n][k] = W[k][n])
#define OFF_DEL2 0
#define OFF_GAM1 16384
#define OFF_GAM2 32768
#define OFF_FC1  49152
#define OFF_PHI  57344
#define OFF_PSI  73728
#define OFF_ALF  90112
#define OFF_DPT1 106496
#define OFF_DPT2 122880
#define WT_TOTAL 139264

// ---------------------------------------------------------------------------
// Kernel 0: transpose+convert all 9 matmul weights -> bf16 Wt[n][K] linear.
// ---------------------------------------------------------------------------
__global__ __launch_bounds__(256) void prep_kernel(
    const float* __restrict__ Wdel2, const float* __restrict__ Wgam1,
    const float* __restrict__ Wgam2, const float* __restrict__ Wfc1,
    const float* __restrict__ Wphi, const float* __restrict__ Wpsi,
    const float* __restrict__ Walpha, const float* __restrict__ Wdpt1,
    const float* __restrict__ Wdpt2, u16* __restrict__ Wt) {
    int idx = blockIdx.x * 256 + threadIdx.x;       // 0..139263
    const float* W;
    int n, k;
    if (idx < OFF_FC1) {
        int m = idx >> 14, r = idx & 16383;
        W = (m == 0) ? Wdel2 : (m == 1) ? Wgam1 : Wgam2;
        n = r >> 7; k = r & 127;
    } else if (idx < OFF_PHI) {
        int r = idx - OFF_FC1;
        W = Wfc1; n = r >> 6; k = r & 63;
    } else {
        int r = idx - OFF_PHI;
        int m = r >> 14; r &= 16383;
        W = (m == 0) ? Wphi : (m == 1) ? Wpsi : (m == 2) ? Walpha : (m == 3) ? Wdpt1 : Wdpt2;
        n = r >> 7; k = r & 127;
    }
    Wt[idx] = f2b(W[k * 128 + n]);
}

// ---------------------------------------------------------------------------
// Kernel 1 (v2): exact kNN. 512 blocks x 256 threads. (measured-good)
// ---------------------------------------------------------------------------
__global__ __launch_bounds__(256) void knn_kernel(const float* __restrict__ x,
                                                  int* __restrict__ knn) {
    __shared__ float4 sx[Nq];                       // 32 KB
    __shared__ float sLd[32][8][17];
    __shared__ int   sLi[32][8][17];
    const int b = blockIdx.x >> 6;
    const int q0 = (blockIdx.x & 63) * 32;
    const float* xb = x + b * Nq * 3;
    for (int j = threadIdx.x; j < Nq; j += 256) {
        float x0 = xb[j * 3 + 0], x1 = xb[j * 3 + 1], x2 = xb[j * 3 + 2];
        // replicate jnp.sum(x*x): no fma contraction
        float n2 = __fadd_rn(__fadd_rn(__fmul_rn(x0, x0), __fmul_rn(x1, x1)),
                             __fmul_rn(x2, x2));
        sx[j] = make_float4(x0, x1, x2, n2);
    }
    __syncthreads();
    const int q = threadIdx.x & 31;
    const int sub = threadIdx.x >> 5;
    const float4 qv = sx[q0 + q];
    float bd[Kq];
    int bj[Kq];
#pragma unroll
    for (int s = 0; s < Kq; ++s) { bd[s] = INFINITY; bj[s] = 0; }
    const int j0 = sub * 256;
    for (int i = 0; i < 256; ++i) {
        const int j = j0 + i;
        float4 p = sx[j];
        float dot = __fadd_rn(__fadd_rn(__fmul_rn(qv.x, p.x), __fmul_rn(qv.y, p.y)),
                              __fmul_rn(qv.z, p.z));
        float d = __fsub_rn(__fadd_rn(qv.w, p.w), __fmul_rn(2.0f, dot));
        if (d < bd[Kq - 1]) {                       // strict <: stable
            bd[Kq - 1] = d; bj[Kq - 1] = j;
#pragma unroll
            for (int s = Kq - 1; s >= 1; --s) {
                if (bd[s] < bd[s - 1]) {
                    float td = bd[s]; bd[s] = bd[s - 1]; bd[s - 1] = td;
                    int tj = bj[s]; bj[s] = bj[s - 1]; bj[s - 1] = tj;
                }
            }
        }
    }
#pragma unroll
    for (int s = 0; s < Kq; ++s) { sLd[q][sub][s] = bd[s]; sLi[q][sub][s] = bj[s]; }
    __syncthreads();
    if (threadIdx.x < 32) {
        const int mq = threadIdx.x;
        int pos[8]; float hd[8]; int hi[8];
#pragma unroll
        for (int s = 0; s < 8; ++s) {
            pos[s] = 1; hd[s] = sLd[mq][s][0]; hi[s] = sLi[mq][s][0];
        }
        int* o = knn + (b * Nq + q0 + mq) * Kq;
#pragma unroll
        for (int oi = 0; oi < Kq; ++oi) {
            float bdv = hd[0]; int biv = hi[0]; int bs = 0;
#pragma unroll
            for (int s = 1; s < 8; ++s) {
                bool take = (hd[s] < bdv) || (hd[s] == bdv && hi[s] < biv);
                if (take) { bdv = hd[s]; biv = hi[s]; bs = s; }
            }
            o[oi] = biv;
#pragma unroll
            for (int s = 0; s < 8; ++s) {           // static-index update
                if (s == bs) {
                    int pp = pos[s] < Kq ? pos[s] : (Kq - 1);
                    bool ok = pos[s] < Kq;
                    hd[s] = ok ? sLd[mq][s][pp] : INFINITY;
                    hi[s] = ok ? sLi[mq][s][pp] : 0x7fffffff;
                    pos[s]++;
                }
            }
        }
    }
}

// ---------------------------------------------------------------------------
// Shared MFMA helpers (feat kernel). XOR swizzle byte ^= (row&7)<<4.
// ---------------------------------------------------------------------------
template <int BYTES, int ROWBYTES>
__device__ __forceinline__ void stageW(const u16* __restrict__ src,
                                       u16* __restrict__ sW, int t) {
#pragma unroll
    for (int c = 0; c < BYTES / 4096; ++c) {
        int lin = c * 4096 + t * 16;
        int n = lin / ROWBYTES;
        int o = lin % ROWBYTES;
        bf16x8v v = *(const bf16x8v*)((const char*)src + lin);
        *(bf16x8v*)((char*)sW + n * ROWBYTES + (o ^ ((n & 7) << 4))) = v;
    }
}

__device__ __forceinline__ void mfma_k128(const u16* __restrict__ sA,
                                          const u16* __restrict__ sW,
                                          int colbase, int lane,
                                          f32x4v (&acc)[4][2]) {
    const int kg = lane >> 4;
    const int l15 = lane & 15;
#pragma unroll
    for (int ks = 0; ks < 4; ++ks) {
        bf16x8v a[4], bfr[2];
#pragma unroll
        for (int m = 0; m < 4; ++m) {
            int row = m * 16 + l15;
            int o = (ks * 64 + kg * 16) ^ ((row & 7) << 4);
            a[m] = *(const bf16x8v*)((const char*)sA + row * 256 + o);
        }
#pragma unroll
        for (int nt = 0; nt < 2; ++nt) {
            int n = colbase + nt * 16 + l15;
            int o = (ks * 64 + kg * 16) ^ ((n & 7) << 4);
            bfr[nt] = *(const bf16x8v*)((const char*)sW + n * 256 + o);
        }
#pragma unroll
        for (int m = 0; m < 4; ++m)
#pragma unroll
            for (int nt = 0; nt < 2; ++nt)
                acc[m][nt] = __builtin_amdgcn_mfma_f32_16x16x32_bf16(a[m], bfr[nt], acc[m][nt], 0, 0, 0);
    }
}

__device__ __forceinline__ void mfma_k64(const u16* __restrict__ sA,
                                         const u16* __restrict__ sW,
                                         int colbase, int lane,
                                         f32x4v (&acc)[4][2]) {
    const int kg = lane >> 4;
    const int l15 = lane & 15;
#pragma unroll
    for (int ks = 0; ks < 2; ++ks) {
        bf16x8v a[4], bfr[2];
#pragma unroll
        for (int m = 0; m < 4; ++m) {
            int row = m * 16 + l15;
            int o = (ks * 64 + kg * 16) ^ ((row & 7) << 4);
            a[m] = *(const bf16x8v*)((const char*)sA + row * 128 + o);
        }
#pragma unroll
        for (int nt = 0; nt < 2; ++nt) {
            int n = colbase + nt * 16 + l15;
            int o = (ks * 64 + kg * 16) ^ ((n & 7) << 4);
            bfr[nt] = *(const bf16x8v*)((const char*)sW + n * 128 + o);
        }
#pragma unroll
        for (int m = 0; m < 4; ++m)
#pragma unroll
            for (int nt = 0; nt < 2; ++nt)
                acc[m][nt] = __builtin_amdgcn_mfma_f32_16x16x32_bf16(a[m], bfr[nt], acc[m][nt], 0, 0, 0);
    }
}

// ---------------------------------------------------------------------------
// Kernel 2 (MFMA): per-point features, 64 points/block, 256 blocks x 4 waves.
// (unchanged from round 3/5)
// ---------------------------------------------------------------------------
__global__ __launch_bounds__(256, 2) void feat_kernel(
    const float* __restrict__ in_f, const u16* __restrict__ Wt,
    const float* __restrict__ bfc1, const float* __restrict__ bdpt1,
    const float* __restrict__ bdpt2,
    float* __restrict__ base, u16* __restrict__ psiB, u16* __restrict__ alphaB) {
    __shared__ __align__(16) u16 sIn[64 * 64];      // 8 KB
    __shared__ __align__(16) u16 sF[64 * 128];      // 16 KB
    __shared__ __align__(16) u16 sW[128 * 128];     // 32 KB
    const int t = threadIdx.x;
    const int lane = t & 63;
    const int w = t >> 6;
    const int kg = lane >> 4;
    const int l15 = lane & 15;
    const int p0 = blockIdx.x * 64;

    {
        const int r = t >> 2;
        const int c0 = (t & 3) * 16;
        const float* src = &in_f[(size_t)(p0 + r) * 64 + c0];
        float4 v0 = *(const float4*)(src + 0);
        float4 v1 = *(const float4*)(src + 4);
        float4 v2 = *(const float4*)(src + 8);
        float4 v3 = *(const float4*)(src + 12);
        bf16x8v lo, hi;
        lo[0] = (__bf16)v0.x; lo[1] = (__bf16)v0.y; lo[2] = (__bf16)v0.z; lo[3] = (__bf16)v0.w;
        lo[4] = (__bf16)v1.x; lo[5] = (__bf16)v1.y; lo[6] = (__bf16)v1.z; lo[7] = (__bf16)v1.w;
        hi[0] = (__bf16)v2.x; hi[1] = (__bf16)v2.y; hi[2] = (__bf16)v2.z; hi[3] = (__bf16)v2.w;
        hi[4] = (__bf16)v3.x; hi[5] = (__bf16)v3.y; hi[6] = (__bf16)v3.z; hi[7] = (__bf16)v3.w;
        const int swz = (r & 7) << 4;
        *(bf16x8v*)((char*)sIn + r * 128 + ((c0 * 2) ^ swz)) = lo;
        *(bf16x8v*)((char*)sIn + r * 128 + (((c0 + 8) * 2) ^ swz)) = hi;
    }

    f32x4v acc[4][2], accPhi[4][2];

    {
        float bv0 = bfc1[w * 32 + l15];
        float bv1 = bfc1[w * 32 + 16 + l15];
#pragma unroll
        for (int m = 0; m < 4; ++m) { acc[m][0] = f32x4v{bv0, bv0, bv0, bv0}; acc[m][1] = f32x4v{bv1, bv1, bv1, bv1}; }
    }
    stageW<16384, 128>(Wt + OFF_FC1, sW, t);
    __syncthreads();
    mfma_k64(sIn, sW, w * 32, lane, acc);

#pragma unroll
    for (int m = 0; m < 4; ++m)
#pragma unroll
        for (int nt = 0; nt < 2; ++nt)
#pragma unroll
            for (int rr = 0; rr < 4; ++rr) {
                int row = m * 16 + kg * 4 + rr;
                int col = w * 32 + nt * 16 + l15;
                *(__bf16*)((char*)sF + row * 256 + ((col * 2) ^ ((row & 7) << 4))) = (__bf16)acc[m][nt][rr];
            }

#pragma unroll
    for (int m = 0; m < 4; ++m) { accPhi[m][0] = f32x4v{0, 0, 0, 0}; accPhi[m][1] = f32x4v{0, 0, 0, 0}; }
    __syncthreads();
    stageW<32768, 256>(Wt + OFF_PHI, sW, t);
    __syncthreads();
    mfma_k128(sF, sW, w * 32, lane, accPhi);

#pragma unroll
    for (int m = 0; m < 4; ++m) { acc[m][0] = f32x4v{0, 0, 0, 0}; acc[m][1] = f32x4v{0, 0, 0, 0}; }
    __syncthreads();
    stageW<32768, 256>(Wt + OFF_PSI, sW, t);
    __syncthreads();
    mfma_k128(sF, sW, w * 32, lane, acc);
#pragma unroll
    for (int m = 0; m < 4; ++m)
#pragma unroll
        for (int nt = 0; nt < 2; ++nt)
#pragma unroll
            for (int rr = 0; rr < 4; ++rr) {
                int row = m * 16 + kg * 4 + rr;
                int col = w * 32 + nt * 16 + l15;
                psiB[(size_t)(p0 + row) * 128 + col] = f2b(acc[m][nt][rr]);
            }

#pragma unroll
    for (int m = 0; m < 4; ++m) { acc[m][0] = f32x4v{0, 0, 0, 0}; acc[m][1] = f32x4v{0, 0, 0, 0}; }
    __syncthreads();
    stageW<32768, 256>(Wt + OFF_ALF, sW, t);
    __syncthreads();
    mfma_k128(sF, sW, w * 32, lane, acc);
#pragma unroll
    for (int m = 0; m < 4; ++m)
#pragma unroll
        for (int nt = 0; nt < 2; ++nt)
#pragma unroll
            for (int rr = 0; rr < 4; ++rr) {
                int row = m * 16 + kg * 4 + rr;
                int col = w * 32 + nt * 16 + l15;
                alphaB[(size_t)(p0 + row) * 128 + col] = f2b(acc[m][nt][rr]);
            }

    {
        float bv0 = bdpt1[w * 32 + l15];
        float bv1 = bdpt1[w * 32 + 16 + l15];
#pragma unroll
        for (int m = 0; m < 4; ++m) { acc[m][0] = f32x4v{bv0, bv0, bv0, bv0}; acc[m][1] = f32x4v{bv1, bv1, bv1, bv1}; }
    }
    __syncthreads();
    stageW<32768, 256>(Wt + OFF_DPT1, sW, t);
    __syncthreads();
    mfma_k128(sF, sW, w * 32, lane, acc);
    __syncthreads();
#pragma unroll
    for (int m = 0; m < 4; ++m)
#pragma unroll
        for (int nt = 0; nt < 2; ++nt)
#pragma unroll
            for (int rr = 0; rr < 4; ++rr) {
                int row = m * 16 + kg * 4 + rr;
                int col = w * 32 + nt * 16 + l15;
                *(__bf16*)((char*)sF + row * 256 + ((col * 2) ^ ((row & 7) << 4))) =
                    (__bf16)fmaxf(acc[m][nt][rr], 0.f);
            }

    {
        float bv0 = bdpt2[w * 32 + l15];
        float bv1 = bdpt2[w * 32 + 16 + l15];
#pragma unroll
        for (int m = 0; m < 4; ++m) { acc[m][0] = f32x4v{bv0, bv0, bv0, bv0}; acc[m][1] = f32x4v{bv1, bv1, bv1, bv1}; }
    }
    __syncthreads();
    stageW<32768, 256>(Wt + OFF_DPT2, sW, t);
    __syncthreads();
    mfma_k128(sF, sW, w * 32, lane, acc);
#pragma unroll
    for (int m = 0; m < 4; ++m)
#pragma unroll
        for (int nt = 0; nt < 2; ++nt)
#pragma unroll
            for (int rr = 0; rr < 4; ++rr) {
                int row = m * 16 + kg * 4 + rr;
                int col = w * 32 + nt * 16 + l15;
                base[(size_t)(p0 + row) * 128 + col] = acc[m][nt][rr] + accPhi[m][nt][rr];
            }
}

// ---------------------------------------------------------------------------
// Kernel 3 (v7): 1024 blocks x 512 threads, 4 chunks x 4 points.
// = round-8 structure with __launch_bounds__(512, 2): LDS (68KB) caps at
// 2 blocks/CU anyway, so the (512,4) 64-VGPR cap bought nothing and caused
// the 250 MB scratch spill (rounds 7-8). 128 VGPRs fits the prefetch set.
// ---------------------------------------------------------------------------
__device__ __forceinline__ void mfma_ldsB(const u16* __restrict__ sA,
                                          const u16* __restrict__ sW,
                                          int colW, int kg, int l15,
                                          f32x4v (&acc)[4]) {
#pragma unroll
    for (int ks = 0; ks < 4; ++ks) {
        bf16x8v a[4], bb;
#pragma unroll
        for (int m = 0; m < 4; ++m) {
            int row = m * 16 + l15;
            int o = (ks * 64 + kg * 16) ^ ((row & 7) << 4);
            a[m] = *(const bf16x8v*)((const char*)sA + row * 256 + o);
        }
        {
            int o = (ks * 64 + kg * 16) ^ ((colW & 7) << 4);
            bb = *(const bf16x8v*)((const char*)sW + colW * 256 + o);
        }
#pragma unroll
        for (int m = 0; m < 4; ++m)
            acc[m] = __builtin_amdgcn_mfma_f32_16x16x32_bf16(a[m], bb, acc[m], 0, 0, 0);
    }
}

__device__ __forceinline__ void mfma_regB(const u16* __restrict__ sA,
                                          const bf16x8v (&wB)[4],
                                          int kg, int l15,
                                          f32x4v (&acc)[4]) {
#pragma unroll
    for (int ks = 0; ks < 4; ++ks) {
#pragma unroll
        for (int m = 0; m < 4; ++m) {
            int row = m * 16 + l15;
            int o = (ks * 64 + kg * 16) ^ ((row & 7) << 4);
            bf16x8v a = *(const bf16x8v*)((const char*)sA + row * 256 + o);
            acc[m] = __builtin_amdgcn_mfma_f32_16x16x32_bf16(a, wB[ks], acc[m], 0, 0, 0);
        }
    }
}

__global__ __launch_bounds__(512, 2) void main_kernel(
    const float* __restrict__ x, const float* __restrict__ in_f,
    const float* __restrict__ Wdel1, const float* __restrict__ bdel1,
    const float* __restrict__ bdel2,
    const float* __restrict__ bgam1, const float* __restrict__ bgam2,
    const float* __restrict__ Wfc2, const float* __restrict__ bfc2,
    const float* __restrict__ base, const u16* __restrict__ psiB,
    const u16* __restrict__ alphaB, const int* __restrict__ knn,
    const u16* __restrict__ Wt, float* __restrict__ out) {
    __shared__ __align__(16) u16 sWd2[128 * 128];   // 32 KB del2 weights (swz)
    __shared__ __align__(16) u16 sA[2][64 * 128];   // 2x16 KB ping-pong (swz)
    __shared__ float sWd1[512];                     // Wdel1 rows + bias at 384
    __shared__ float sY[4][128];

    const int t = threadIdx.x;
    const int lane = t & 63;
    const int w = t >> 6;                            // wave 0..7
    const int kg = lane >> 4;
    const int l15 = lane & 15;
    const int colW = w * 16 + l15;                   // this thread's out column

    const int pbase = blockIdx.x * 16;               // 16 points per block
    const int b = pbase >> 11;
    const int bN = b * Nq;
    const int hr = t >> 3;                           // B-phase row 0..63
    const int hc0 = (t & 7) * 16;                    // B-phase col base

    // ---- chunk-0 B inputs (issued early; drained at prologue barrier) ----
    int pB = pbase + (hr >> 4);
    int jB = knn[pB * Kq + (hr & 15)];
    float cxq0 = x[(size_t)pB * 3 + 0];
    float cxq1 = x[(size_t)pB * 3 + 1];
    float cxq2 = x[(size_t)pB * 3 + 2];
    float cxn0 = x[(size_t)(bN + jB) * 3 + 0];
    float cxn1 = x[(size_t)(bN + jB) * 3 + 1];
    float cxn2 = x[(size_t)(bN + jB) * 3 + 2];

    // ---- prologue: del2 weights -> LDS, Wdel1 -> LDS, gam weights -> regs ----
#pragma unroll
    for (int c = 0; c < 4; ++c) {
        int lin = c * 8192 + t * 16;
        int n = lin >> 8;
        int o = lin & 255;
        bf16x8v v = *(const bf16x8v*)((const char*)(Wt + OFF_DEL2) + lin);
        *(bf16x8v*)((char*)sWd2 + n * 256 + (o ^ ((n & 7) << 4))) = v;
    }
    sWd1[t] = (t < 384) ? Wdel1[t] : bdel1[t - 384];
    bf16x8v wG1[4], wG2[4];
#pragma unroll
    for (int ks = 0; ks < 4; ++ks) {
        size_t off = (size_t)colW * 128 + ks * 32 + kg * 8;
        wG1[ks] = *(const bf16x8v*)(Wt + OFF_GAM1 + off);
        wG2[ks] = *(const bf16x8v*)(Wt + OFF_GAM2 + off);
    }
    const float bD = bdel2[colW];
    const float bG1 = bgam1[colW];
    const float bG2 = bgam2[colW];
    const float bOq = bfc2[(t & 127) >> 1];
    __syncthreads();    // prologue fence: sWd1/sWd2 visible before chunk 0

    for (int c = 0; c < 4; ++c) {
        const int p0 = pbase + c * 4;
        u16* sAh = sA[c & 1];                        // h1 then g1
        u16* sAp = sA[1 - (c & 1)];                  // pre

        // ---- B: h1 = relu(diff @ Wdel1 + b) -> sAh ----
        {
            const float dx = cxq0 - cxn0;
            const float dy = cxq1 - cxn1;
            const float dz = cxq2 - cxn2;
            const int swzB = (hr & 7) << 4;
#pragma unroll
            for (int hh = 0; hh < 2; ++hh) {
                bf16x8v hv;
#pragma unroll
                for (int c4 = 0; c4 < 2; ++c4) {
                    const int cc = hc0 + hh * 8 + c4 * 4;
                    float4 wx = *(const float4*)&sWd1[cc];
                    float4 wy = *(const float4*)&sWd1[128 + cc];
                    float4 wz = *(const float4*)&sWd1[256 + cc];
                    float4 b4 = *(const float4*)&sWd1[384 + cc];
                    hv[c4 * 4 + 0] = (__bf16)fmaxf(fmaf(dz, wz.x, fmaf(dy, wy.x, fmaf(dx, wx.x, b4.x))), 0.f);
                    hv[c4 * 4 + 1] = (__bf16)fmaxf(fmaf(dz, wz.y, fmaf(dy, wy.y, fmaf(dx, wx.y, b4.y))), 0.f);
                    hv[c4 * 4 + 2] = (__bf16)fmaxf(fmaf(dz, wz.z, fmaf(dy, wy.z, fmaf(dx, wx.z, b4.z))), 0.f);
                    hv[c4 * 4 + 3] = (__bf16)fmaxf(fmaf(dz, wz.w, fmaf(dy, wy.w, fmaf(dx, wx.w, b4.w))), 0.f);
                }
                *(bf16x8v*)((char*)sAh + hr * 256 + (((hc0 + hh * 8) * 2) ^ swzB)) = hv;
            }
        }

        // ---- prefetch: per-thread knn idx, then psi + base (consumed post-MFMA) ----
        int4 ivv[4];
#pragma unroll
        for (int m = 0; m < 4; ++m)
            ivv[m] = *(const int4*)&knn[(p0 + m) * Kq + kg * 4];
        u16 ps[4][4];
        float bs[4];
#pragma unroll
        for (int m = 0; m < 4; ++m) {
            bs[m] = base[(size_t)(p0 + m) * 128 + colW];
            const int ii[4] = {ivv[m].x, ivv[m].y, ivv[m].z, ivv[m].w};
#pragma unroll
            for (int rr = 0; rr < 4; ++rr)
                ps[m][rr] = psiB[(size_t)(bN + ii[rr]) * 128 + colW];
        }
        BARRIER();                                   // bar1: h1 ready

        // ---- del2: delta = h1 @ Wdel2 + b ----
        f32x4v accD[4];
#pragma unroll
        for (int m = 0; m < 4; ++m) accD[m] = f32x4v{bD, bD, bD, bD};
        mfma_ldsB(sAh, sWd2, colW, kg, l15, accD);

        // ---- pre = delta + (base - psi) -> sAp (prefetched regs) ----
#pragma unroll
        for (int m = 0; m < 4; ++m)
#pragma unroll
            for (int rr = 0; rr < 4; ++rr) {
                int row = m * 16 + kg * 4 + rr;
                int off = row * 256 + ((colW * 2) ^ ((row & 7) << 4));
                *(__bf16*)((char*)sAp + off) = (__bf16)(accD[m][rr] + (bs[m] - b2f(ps[m][rr])));
            }
        BARRIER();                                   // bar2: pre ready

        // ---- gam1 (reg weights): g1 = relu(pre @ Wgam1 + b) -> sAh ----
        f32x4v accT[4];
#pragma unroll
        for (int m = 0; m < 4; ++m) accT[m] = f32x4v{bG1, bG1, bG1, bG1};
        mfma_regB(sAp, wG1, kg, l15, accT);
#pragma unroll
        for (int m = 0; m < 4; ++m)
#pragma unroll
            for (int rr = 0; rr < 4; ++rr) {
                int row = m * 16 + kg * 4 + rr;
                int off = row * 256 + ((colW * 2) ^ ((row & 7) << 4));
                *(__bf16*)((char*)sAh + off) = (__bf16)fmaxf(accT[m][rr], 0.f);
            }
        BARRIER();                                   // bar3: g1 ready

        // ---- prefetch alpha (1 stage early; consumed right after gam2) ----
        u16 al[4][4];
#pragma unroll
        for (int m = 0; m < 4; ++m) {
            const int ii[4] = {ivv[m].x, ivv[m].y, ivv[m].z, ivv[m].w};
#pragma unroll
            for (int rr = 0; rr < 4; ++rr)
                al[m][rr] = alphaB[(size_t)(bN + ii[rr]) * 128 + colW];
        }

        // ---- gam2 (reg weights) ----
#pragma unroll
        for (int m = 0; m < 4; ++m) accT[m] = f32x4v{bG2, bG2, bG2, bG2};
        mfma_regB(sAh, wG2, kg, l15, accT);

        // ---- prefetch next-chunk B idx (x loads issued after out) ----
        const int pN = pbase + (c + 1) * 4 + (hr >> 4);
        int jN = 0;
        if (c < 3) jN = knn[pN * Kq + (hr & 15)];

        // ---- softmax over k + y (alpha from regs) ----
#pragma unroll
        for (int m = 0; m < 4; ++m) {
            float g0 = accT[m][0], g1v = accT[m][1], g2 = accT[m][2], g3 = accT[m][3];
            float mx = fmaxf(fmaxf(g0, g1v), fmaxf(g2, g3));
            mx = fmaxf(mx, __shfl_xor(mx, 16, 64));
            mx = fmaxf(mx, __shfl_xor(mx, 32, 64));
            float m4 = mx * 0.25f;
            float e0 = expf(0.25f * g0 - m4), e1 = expf(0.25f * g1v - m4);
            float e2 = expf(0.25f * g2 - m4), e3 = expf(0.25f * g3 - m4);
            float s = e0 + e1 + e2 + e3;
            s += __shfl_xor(s, 16, 64);
            s += __shfl_xor(s, 32, 64);
            float y = fmaf(e0, b2f(al[m][0]) + accD[m][0],
                      fmaf(e1, b2f(al[m][1]) + accD[m][1],
                      fmaf(e2, b2f(al[m][2]) + accD[m][2],
                           e3 * (b2f(al[m][3]) + accD[m][3]))));
            y += __shfl_xor(y, 16, 64);
            y += __shfl_xor(y, 32, 64);
            if (kg == 0) sY[m][colW] = y / s;
        }
        BARRIER();                                   // bar4: sY ready

        // ---- out = y @ Wfc2 + b + in_f (all 8 waves, lane-paired) ----
        {
            const int p = t >> 7;                    // 0..3
            const int q = (t & 127) >> 1;
            const int half = t & 1;
            const int gp = p0 + p;
            float a = 0.f;
            const float* wcol = Wfc2 + (half * 64) * 64 + q;
#pragma unroll 16
            for (int d = 0; d < 64; ++d)
                a = fmaf(sY[p][half * 64 + d], wcol[d * 64], a);
            a += __shfl_xor(a, 1, 64);
            if (half == 0)
                out[(size_t)gp * 64 + q] = a + bOq + in_f[(size_t)gp * 64 + q];
        }

        // ---- prefetch next-chunk x (covered by loop-back to B compute) ----
        if (c < 3) {
            cxq0 = x[(size_t)pN * 3 + 0];
            cxq1 = x[(size_t)pN * 3 + 1];
            cxq2 = x[(size_t)pN * 3 + 2];
            cxn0 = x[(size_t)(bN + jN) * 3 + 0];
            cxn1 = x[(size_t)(bN + jN) * 3 + 1];
            cxn2 = x[(size_t)(bN + jN) * 3 + 2];
        }
    }
}

// ---------------------------------------------------------------------------
extern "C" void kernel_launch(void* const* d_in, const int* in_sizes, int n_in,
                              void* d_out, int out_size, void* d_ws, size_t ws_size,
                              hipStream_t stream) {
    const float* x     = (const float*)d_in[0];
    const float* in_f  = (const float*)d_in[1];
    const float* Wfc1  = (const float*)d_in[2];
    const float* bfc1  = (const float*)d_in[3];
    const float* Wphi  = (const float*)d_in[4];
    const float* Wpsi  = (const float*)d_in[5];
    const float* Walpha= (const float*)d_in[6];
    const float* Wdpt1 = (const float*)d_in[7];
    const float* bdpt1 = (const float*)d_in[8];
    const float* Wdpt2 = (const float*)d_in[9];
    const float* bdpt2 = (const float*)d_in[10];
    const float* Wgam1 = (const float*)d_in[11];
    const float* bgam1 = (const float*)d_in[12];
    const float* Wgam2 = (const float*)d_in[13];
    const float* bgam2 = (const float*)d_in[14];
    const float* Wdel1 = (const float*)d_in[15];
    const float* bdel1 = (const float*)d_in[16];
    const float* Wdel2 = (const float*)d_in[17];
    const float* bdel2 = (const float*)d_in[18];
    const float* Wfc2  = (const float*)d_in[19];
    const float* bfc2  = (const float*)d_in[20];
    float* out = (float*)d_out;

    // ws: base f32 (8MB) | psiB bf16 (4MB) | alphaB bf16 (4MB) | knn (1MB) | Wt (272KB)
    float* base   = (float*)d_ws;
    u16*   psiB   = (u16*)(base + (size_t)BNq * Dq);
    u16*   alphaB = psiB + (size_t)BNq * Dq;
    int*   knn    = (int*)(alphaB + (size_t)BNq * Dq);
    u16*   Wt     = (u16*)(knn + (size_t)BNq * Kq);

    prep_kernel<<<WT_TOTAL / 256, 256, 0, stream>>>(Wdel2, Wgam1, Wgam2, Wfc1, Wphi,
                                                    Wpsi, Walpha, Wdpt1, Wdpt2, Wt);
    knn_kernel<<<512, 256, 0, stream>>>(x, knn);
    feat_kernel<<<BNq / 64, 256, 0, stream>>>(in_f, Wt, bfc1, bdpt1, bdpt2,
                                              base, psiB, alphaB);
    main_kernel<<<BNq / 16, 512, 0, stream>>>(x, in_f, Wdel1, bdel1, bdel2,
                                              bgam1, bgam2, Wfc2, bfc2,
                                              base, psiB, alphaB, knn, Wt, out);
}